// Round 12
// baseline (442.221 us; speedup 1.0000x reference)
//
#include <hip/hip_runtime.h>
#include <hip/hip_fp16.h>

#define NN 50000
#define NE 800000
#define CIN 64
#define COUT 64
#define HD 32
#define NL 4
#define NBUK 196      // ceil(NN/256)
#define BUKSH 8       // bucket(r) = r >> 8
#define EPB 3125      // NE / 256 (exact)
#define MAXB 4864     // bucket capacity (mean 4096, sigma 64 -> 12 sigma headroom)
#define EMB_BLKS 196  // ceil(NN/256)

typedef float f32x4 __attribute__((ext_vector_type(4)));
typedef _Float16 half8 __attribute__((ext_vector_type(8)));

__device__ __forceinline__ float silu_f(float v) {
    return v * __builtin_amdgcn_rcpf(1.0f + __expf(-v));
}

// ========== K1: fused prologue — embed (blocks 0..195) | S1 hist (196..451) | prep (452)
__global__ __launch_bounds__(256) void prologue_kernel(
    const float* __restrict__ data, const float* __restrict__ pos,
    const float* __restrict__ tptr,
    const float* __restrict__ W, const float* __restrict__ b,
    const float* __restrict__ eW1_0,
    const int* __restrict__ row,
    const float* __restrict__ eW2, const float* __restrict__ cW1,
    float* __restrict__ h, float* __restrict__ x4,
    __half* __restrict__ Hrh, __half* __restrict__ Hch,
    float* __restrict__ aggM, float* __restrict__ aggX4,
    int* __restrict__ resv,
    __half* __restrict__ w2B, __half* __restrict__ cW1B)
{
    int blk = blockIdx.x;
    int tid = threadIdx.x;

    if (blk < EMB_BLKS) {
        // ---------------- embed role ----------------
        int n = blk * 256 + tid;
        if (n >= NN) return;
        float t = tptr[0];
        float d[CIN];
        const float4* dp = (const float4*)(data + (size_t)n * CIN);
#pragma unroll
        for (int i = 0; i < CIN / 4; i++) {
            float4 v = dp[i];
            d[4*i+0] = v.x; d[4*i+1] = v.y; d[4*i+2] = v.z; d[4*i+3] = v.w;
        }
        float acc[HD];
#pragma unroll
        for (int j = 0; j < HD; j++) acc[j] = fmaf(t, W[j], b[j]);   // row 0 = t channel
#pragma unroll
        for (int i = 0; i < CIN; i++) {
            float a = d[i];
#pragma unroll
            for (int j = 0; j < HD; j++) acc[j] = fmaf(a, W[(i + 1) * HD + j], acc[j]);
        }
        float4* hp = (float4*)(h + (size_t)n * HD);
#pragma unroll
        for (int j = 0; j < HD / 4; j++)
            hp[j] = make_float4(acc[4*j], acc[4*j+1], acc[4*j+2], acc[4*j+3]);
        ((float4*)x4)[n] = make_float4(pos[n*2+0], pos[n*2+1], 0.0f, 0.0f);

        float a1[HD], a2[HD];
#pragma unroll
        for (int j = 0; j < HD; j++) { a1[j] = 0.0f; a2[j] = 0.0f; }
#pragma unroll
        for (int i = 0; i < HD; i++) {
            float z = acc[i];
#pragma unroll
            for (int j = 0; j < HD; j++) {
                a1[j] = fmaf(z, eW1_0[i * HD + j], a1[j]);
                a2[j] = fmaf(z, eW1_0[(HD + i) * HD + j], a2[j]);
            }
        }
        int w1[16], w2[16];
#pragma unroll
        for (int q = 0; q < 16; q++) {
            __half2 p1 = __floats2half2_rn(a1[2*q], a1[2*q+1]);
            __half2 p2 = __floats2half2_rn(a2[2*q], a2[2*q+1]);
            w1[q] = *(int*)&p1;
            w2[q] = *(int*)&p2;
        }
        int4* rp = (int4*)(Hrh + (size_t)n * HD);
        int4* cp = (int4*)(Hch + (size_t)n * HD);
#pragma unroll
        for (int q = 0; q < 4; q++) {
            rp[q] = make_int4(w1[4*q], w1[4*q+1], w1[4*q+2], w1[4*q+3]);
            cp[q] = make_int4(w2[4*q], w2[4*q+1], w2[4*q+2], w2[4*q+3]);
        }
        float4 z4 = make_float4(0.f, 0.f, 0.f, 0.f);
        float4* za = (float4*)(aggM + (size_t)n * HD);
#pragma unroll
        for (int j = 0; j < HD/4; j++) za[j] = z4;
        ((float4*)aggX4)[n] = z4;
    } else if (blk < EMB_BLKS + 256) {
        // ---------------- S1 role: per-chunk bucket histogram -> resv
        __shared__ int lb[256];
        int sb = blk - EMB_BLKS;
        lb[tid] = 0;
        __syncthreads();
        int base = sb * EPB;
        for (int i = tid; i < EPB; i += 256)
            atomicAdd(&lb[row[base + i] >> BUKSH], 1);
        __syncthreads();
        if (tid < NBUK) resv[sb * NBUK + tid] = lb[tid];
    } else {
        // ---------------- prep role: pack W2 / cW1 into MFMA B-fragment order (f16)
        if (tid >= 128) return;
        int nt = tid >> 6;
        int wl = tid & 63;
        int rsel = wl & 15, ksel = wl >> 4;
        for (int l = 0; l < NL; l++) {
#pragma unroll
            for (int e = 0; e < 8; e++) {
                int k = 8 * ksel + e;
                int j = 16 * nt + rsel;
                size_t o = ((size_t)(l * 2 + nt) * 64 + wl) * 8 + e;
                w2B[o]  = __float2half(eW2[(size_t)l * HD * HD + k * HD + j]);
                cW1B[o] = __float2half(cW1[(size_t)l * HD * HD + k * HD + j]);
            }
        }
    }
}

// ========== K2: S3' — partition into buckets; inline bucket scan from resv ==========
__global__ __launch_bounds__(256) void sortS3_kernel(
    const int* __restrict__ row, const int* __restrict__ col,
    const float* __restrict__ eattr,
    const int* __restrict__ resv,
    int4* __restrict__ tmp, int* __restrict__ bbase_g)
{
    __shared__ int4 st[EPB];           // 50 KB
    __shared__ int sd[256];
    __shared__ int lcnt_s[NBUK];
    __shared__ int lbex_s[NBUK];
    __shared__ int g_s[NBUK];
    __shared__ int lcur[NBUK];
    int tid = threadIdx.x;
    int bb = blockIdx.x;
    int base = bb * EPB;

    int myCnt = (tid < NBUK) ? resv[bb * NBUK + tid] : 0;
    if (tid < NBUK) { lcnt_s[tid] = myCnt; lcur[tid] = 0; }
    sd[tid] = myCnt;
    __syncthreads();
    for (int off = 1; off < 256; off <<= 1) {
        int t = (tid >= off) ? sd[tid - off] : 0;
        __syncthreads();
        sd[tid] += t;
        __syncthreads();
    }
    if (tid < NBUK) lbex_s[tid] = sd[tid] - myCnt;
    __syncthreads();

    int tot = 0, pre = 0;
    if (tid < NBUK) {
        for (int b2 = 0; b2 < 256; b2++) {
            int cv = resv[b2 * NBUK + tid];
            tot += cv;
            if (b2 < bb) pre += cv;
        }
    }
    sd[tid] = (tid < NBUK) ? tot : 0;
    __syncthreads();
    for (int off = 1; off < 256; off <<= 1) {
        int t = (tid >= off) ? sd[tid - off] : 0;
        __syncthreads();
        sd[tid] += t;
        __syncthreads();
    }
    if (tid < NBUK) {
        int bbase_k = sd[tid] - tot;
        g_s[tid] = bbase_k + pre;
        if (bb == 0) bbase_g[tid] = bbase_k;
    }
    if (bb == 0 && tid == 255) bbase_g[NBUK] = sd[255];   // == NE
    __syncthreads();

    for (int i = tid; i < EPB; i += 256) {
        int e = base + i;
        int r = row[e];
        int bk = r >> BUKSH;
        int p = lbex_s[bk] + atomicAdd(&lcur[bk], 1);
        st[p] = make_int4(r, col[e], __float_as_int(eattr[e]), 0);
    }
    __syncthreads();
    int wid = tid >> 6, lane = tid & 63;
    for (int k = wid; k < NBUK; k += 4) {
        int L = lcnt_s[k];
        int g = g_s[k];
        int o = lbex_s[k];
        for (int i = lane; i < L; i += 64)
            tmp[g + i] = st[o + i];
    }
}

// ========== K3: S4 — within-bucket node sort; rowstart + sedge coalesced ==========
__global__ __launch_bounds__(256) void sortS4_kernel(
    const int4* __restrict__ tmp, const int* __restrict__ bbase,
    int4* __restrict__ sedge, int* __restrict__ rowstart)
{
    __shared__ int4 st[MAXB];          // 76 KB
    __shared__ int lcnt[256], lex[256], lcur[256], sd[256];
    int tid = threadIdx.x;
    int k = blockIdx.x;
    int lo = bbase[k], hi = bbase[k + 1];
    int nE = hi - lo;
    int nodeBase = k << BUKSH;
    lcnt[tid] = 0; lcur[tid] = 0;
    __syncthreads();
    for (int i = tid; i < nE; i += 256)
        atomicAdd(&lcnt[tmp[lo + i].x - nodeBase], 1);
    __syncthreads();
    int v = lcnt[tid];
    sd[tid] = v;
    __syncthreads();
    for (int off = 1; off < 256; off <<= 1) {
        int t = (tid >= off) ? sd[tid - off] : 0;
        __syncthreads();
        sd[tid] += t;
        __syncthreads();
    }
    lex[tid] = sd[tid] - v;
    int n = nodeBase + tid;
    if (n < NN) rowstart[n] = lo + lex[tid];
    if (k == NBUK - 1 && tid == 0) rowstart[NN] = NE;
    __syncthreads();
    for (int i = tid; i < nE; i += 256) {
        int4 e = tmp[lo + i];
        int ln = e.x - nodeBase;
        int p = lex[ln] + atomicAdd(&lcur[ln], 1);
        st[p] = e;
    }
    __syncthreads();
    for (int i = tid; i < nE; i += 256)
        sedge[lo + i] = st[i];
}

// ---- fused edge kernel: 2 edges/thread (256/block), MFMA, segmented agg ----
__global__ __launch_bounds__(128, 3) void edge_fused_kernel(
    const float* __restrict__ x4,
    const int4* __restrict__ sedge,
    const __half* __restrict__ Hrh, const __half* __restrict__ Hch,
    const float* __restrict__ eW1, const float* __restrict__ eb1,
    const float* __restrict__ eb2,
    const __half* __restrict__ w2Bl, const __half* __restrict__ cW1Bl,
    const float* __restrict__ cb1, const float* __restrict__ cW2,
    const int* __restrict__ rowstart,
    float* __restrict__ aggM, float* __restrict__ aggX4)
{
    __shared__ __align__(16) __half At[256][40];   // t1 (f16), then reused for m (f16)
    __shared__ __half sx[256][4];                  // d*phi
    __shared__ float  phib[256];
    __shared__ int snf, snl;
    int tid = threadIdx.x;
    int s_base = blockIdx.x * 256;
    int sA = s_base + tid, sB = sA + 128;          // NE % 256 == 0
    int4 eiA = sedge[sA];
    int4 eiB = sedge[sB];
    int rA = eiA.x, cA = eiA.y, rB = eiB.x, cB = eiB.y;
    float eaA = __int_as_float(eiA.z), eaB = __int_as_float(eiB.z);
    if (tid == 0)   snf = rA;
    if (tid == 127) snl = rB;

    float4 xrA = ((const float4*)x4)[rA];
    float4 xcA = ((const float4*)x4)[cA];
    float4 xrB = ((const float4*)x4)[rB];
    float4 xcB = ((const float4*)x4)[cB];
    float dA0 = xrA.x - xcA.x, dA1 = xrA.y - xcA.y, dA2 = xrA.z - xcA.z;
    float dB0 = xrB.x - xcB.x, dB1 = xrB.y - xcB.y, dB2 = xrB.z - xcB.z;
    float radA = dA0*dA0 + dA1*dA1 + dA2*dA2;
    float radB = dB0*dB0 + dB1*dB1 + dB2*dB2;

    // ---- P1: t1 = silu(Hr[r] + Hc[c] + rad*W1[64,:] + ea*W1[65,:] + b1) -> LDS f16
    const half8* hrA = (const half8*)(Hrh + (size_t)rA * HD);
    const half8* hcA = (const half8*)(Hch + (size_t)cA * HD);
    const half8* hrB = (const half8*)(Hrh + (size_t)rB * HD);
    const half8* hcB = (const half8*)(Hch + (size_t)cB * HD);
    int wbufA[16], wbufB[16];
#pragma unroll
    for (int i = 0; i < 4; i++) {
        half8 s8A = hrA[i] + hcA[i];         // v_pk_add_f16
        half8 s8B = hrB[i] + hcB[i];
#pragma unroll
        for (int kk = 0; kk < 8; kk += 2) {
            int j = 8*i + kk;
            float w64a = eW1[64*HD+j],   w65a = eW1[65*HD+j],   b1a = eb1[j];
            float w64b = eW1[64*HD+j+1], w65b = eW1[65*HD+j+1], b1b = eb1[j+1];
            float vA0 = (float)s8A[kk]   + b1a + radA * w64a + eaA * w65a;
            float vA1 = (float)s8A[kk+1] + b1b + radA * w64b + eaA * w65b;
            float vB0 = (float)s8B[kk]   + b1a + radB * w64a + eaB * w65a;
            float vB1 = (float)s8B[kk+1] + b1b + radB * w64b + eaB * w65b;
            __half2 pA = __floats2half2_rn(silu_f(vA0), silu_f(vA1));
            __half2 pB = __floats2half2_rn(silu_f(vB0), silu_f(vB1));
            wbufA[(j >> 1)] = *(int*)&pA;
            wbufB[(j >> 1)] = *(int*)&pB;
        }
    }
    int4* arowA = (int4*)&At[tid][0];
    int4* arowB = (int4*)&At[tid + 128][0];
#pragma unroll
    for (int q = 0; q < 4; q++) {
        arowA[q] = make_int4(wbufA[4*q], wbufA[4*q+1], wbufA[4*q+2], wbufA[4*q+3]);
        arowB[q] = make_int4(wbufB[4*q], wbufB[4*q+1], wbufB[4*q+2], wbufB[4*q+3]);
    }

    int wl = tid & 63;
    int wbA = tid & 64;              // wave's window for edge-A rows
    int wbB = wbA + 128;             // wave's window for edge-B rows
    int rsel = wl & 15, ksel = wl >> 4;

    // ---- P2: GEMM2 via MFMA (both windows), silu -> m (back to LDS)
    half8 bw0 = ((const half8*)w2Bl)[wl];
    half8 bw1 = ((const half8*)w2Bl)[64 + wl];
    float bc0 = eb2[rsel], bc1 = eb2[16 + rsel];
    f32x4 accA[4][2], accB[4][2];
#pragma unroll
    for (int mt = 0; mt < 4; mt++) {
        accA[mt][0] = (f32x4){bc0, bc0, bc0, bc0};
        accA[mt][1] = (f32x4){bc1, bc1, bc1, bc1};
        accB[mt][0] = (f32x4){bc0, bc0, bc0, bc0};
        accB[mt][1] = (f32x4){bc1, bc1, bc1, bc1};
    }
#pragma unroll
    for (int mt = 0; mt < 4; mt++) {
        half8 afA = *(const half8*)&At[wbA + 16*mt + rsel][8*ksel];
        half8 afB = *(const half8*)&At[wbB + 16*mt + rsel][8*ksel];
        accA[mt][0] = __builtin_amdgcn_mfma_f32_16x16x32_f16(afA, bw0, accA[mt][0], 0, 0, 0);
        accA[mt][1] = __builtin_amdgcn_mfma_f32_16x16x32_f16(afA, bw1, accA[mt][1], 0, 0, 0);
        accB[mt][0] = __builtin_amdgcn_mfma_f32_16x16x32_f16(afB, bw0, accB[mt][0], 0, 0, 0);
        accB[mt][1] = __builtin_amdgcn_mfma_f32_16x16x32_f16(afB, bw1, accB[mt][1], 0, 0, 0);
    }
#pragma unroll
    for (int mt = 0; mt < 4; mt++)
#pragma unroll
        for (int nt = 0; nt < 2; nt++)
#pragma unroll
            for (int q = 0; q < 4; q++) {
                At[wbA + 16*mt + 4*ksel + q][16*nt + rsel] = __float2half(silu_f(accA[mt][nt][q]));
                At[wbB + 16*mt + 4*ksel + q][16*nt + rsel] = __float2half(silu_f(accB[mt][nt][q]));
            }

    // ---- P3: coord MLP via MFMA (both windows)
    half8 cw0 = ((const half8*)cW1Bl)[wl];
    half8 cw1 = ((const half8*)cW1Bl)[64 + wl];
    float cc0 = cb1[rsel], cc1 = cb1[16 + rsel];
    f32x4 cacA[4][2], cacB[4][2];
#pragma unroll
    for (int mt = 0; mt < 4; mt++) {
        cacA[mt][0] = (f32x4){cc0, cc0, cc0, cc0};
        cacA[mt][1] = (f32x4){cc1, cc1, cc1, cc1};
        cacB[mt][0] = (f32x4){cc0, cc0, cc0, cc0};
        cacB[mt][1] = (f32x4){cc1, cc1, cc1, cc1};
    }
#pragma unroll
    for (int mt = 0; mt < 4; mt++) {
        half8 amA = *(const half8*)&At[wbA + 16*mt + rsel][8*ksel];
        half8 amB = *(const half8*)&At[wbB + 16*mt + rsel][8*ksel];
        cacA[mt][0] = __builtin_amdgcn_mfma_f32_16x16x32_f16(amA, cw0, cacA[mt][0], 0, 0, 0);
        cacA[mt][1] = __builtin_amdgcn_mfma_f32_16x16x32_f16(amA, cw1, cacA[mt][1], 0, 0, 0);
        cacB[mt][0] = __builtin_amdgcn_mfma_f32_16x16x32_f16(amB, cw0, cacB[mt][0], 0, 0, 0);
        cacB[mt][1] = __builtin_amdgcn_mfma_f32_16x16x32_f16(amB, cw1, cacB[mt][1], 0, 0, 0);
    }

    // ---- P4: phi = sum_j silu(C1[:,j]) * cW2[j]; reduce across 16-lane cols
    float cw2a = cW2[rsel], cw2b = cW2[16 + rsel];
    float pA[4][4], pB[4][4];
#pragma unroll
    for (int mt = 0; mt < 4; mt++)
#pragma unroll
        for (int q = 0; q < 4; q++) {
            pA[mt][q] = silu_f(cacA[mt][0][q]) * cw2a + silu_f(cacA[mt][1][q]) * cw2b;
            pB[mt][q] = silu_f(cacB[mt][0][q]) * cw2a + silu_f(cacB[mt][1][q]) * cw2b;
        }
#pragma unroll
    for (int dd = 1; dd < 16; dd <<= 1)
#pragma unroll
        for (int mt = 0; mt < 4; mt++)
#pragma unroll
            for (int q = 0; q < 4; q++) {
                pA[mt][q] += __shfl_xor(pA[mt][q], dd);
                pB[mt][q] += __shfl_xor(pB[mt][q], dd);
            }
    if (rsel == 0) {
#pragma unroll
        for (int mt = 0; mt < 4; mt++)
#pragma unroll
            for (int q = 0; q < 4; q++) {
                phib[wbA + 16*mt + 4*ksel + q] = pA[mt][q];
                phib[wbB + 16*mt + 4*ksel + q] = pB[mt][q];
            }
    }
    float phiA = phib[tid];
    float phiB = phib[tid + 128];

    *(__half2*)&sx[tid][0]       = __floats2half2_rn(dA0 * phiA, dA1 * phiA);
    sx[tid][2]                   = __float2half(dA2 * phiA);
    *(__half2*)&sx[tid + 128][0] = __floats2half2_rn(dB0 * phiB, dB1 * phiB);
    sx[tid + 128][2]             = __float2half(dB2 * phiB);
    __syncthreads();

    // ---- P5: block-segmented reduction over 256 edges; 4 lane-groups
    int g = tid >> 5, ch = tid & 31;
    int nf = snf, nl = snl;
    for (int node = nf + g; node <= nl; node += 4) {
        int lo = rowstart[node], hi = rowstart[node + 1];
        int clo = lo - s_base; if (clo < 0) clo = 0;
        int chi = hi - s_base; if (chi > 256) chi = 256;
        if (chi <= clo) continue;                       // zero-degree node in range
        float am = 0.0f;
        for (int j = clo; j < chi; j++) am += __half2float(At[j][ch]);
        bool interior = (lo >= s_base) && (hi <= s_base + 256);
        if (interior) aggM[(size_t)node * HD + ch] = am;
        else          atomicAdd(&aggM[(size_t)node * HD + ch], am);
        if (ch < 3) {
            float ax = 0.0f;
            for (int j = clo; j < chi; j++) ax += __half2float(sx[j][ch]);
            if (interior) aggX4[(size_t)node * 4 + ch] = ax;
            else          atomicAdd(&aggX4[(size_t)node * 4 + ch], ax);
        }
    }
}

// ------- node update (+ f16 Hr/Hc for next layer, or fused output projection) -------
__global__ __launch_bounds__(256) void node_fused_kernel(
    float* __restrict__ h, float* __restrict__ x4,
    float* __restrict__ aggM, float* __restrict__ aggX4,
    const int* __restrict__ rowstart,
    const float* __restrict__ nW1, const float* __restrict__ nb1,
    const float* __restrict__ nW2, const float* __restrict__ nb2,
    const float* __restrict__ eW1n,   // next layer edge_w1 (null on last layer)
    __half* __restrict__ Hrh, __half* __restrict__ Hch,
    const float* __restrict__ Wout, const float* __restrict__ bout,
    float* __restrict__ out)          // non-null on last layer
{
    __shared__ float sIn[8][2*HD];
    __shared__ float sU[8][HD];
    __shared__ float sH[8][HD];
    int local = threadIdx.x >> 5;
    int ch    = threadIdx.x & 31;
    int n = blockIdx.x * 8 + local;          // NN == 6250*8, exact
    float hv = h[(size_t)n * HD + ch];
    float am = aggM[(size_t)n * HD + ch];
    aggM[(size_t)n * HD + ch] = 0.0f;        // re-zero for next layer's boundary atomics
    sIn[local][ch]      = hv;
    sIn[local][HD + ch] = am;
    if (ch < 3) {
        int cnt = rowstart[n + 1] - rowstart[n];
        float cf = (cnt < 1) ? 1.0f : (float)cnt;
        x4[(size_t)n * 4 + ch] += aggX4[(size_t)n * 4 + ch] / cf;
        aggX4[(size_t)n * 4 + ch] = 0.0f;
    }
    __syncthreads();
    float u1 = nb1[ch];
#pragma unroll 8
    for (int i = 0; i < 2*HD; i++) u1 = fmaf(sIn[local][i], nW1[i * HD + ch], u1);
    u1 = silu_f(u1);
    sU[local][ch] = u1;
    __syncthreads();
    float u2 = nb2[ch];
#pragma unroll 8
    for (int i = 0; i < HD; i++) u2 = fmaf(sU[local][i], nW2[i * HD + ch], u2);
    float hn = hv + u2;

    if (eW1n != nullptr) {
        h[(size_t)n * HD + ch] = hn;
        sH[local][ch] = hn;
        __syncthreads();
        float a = 0.0f, b = 0.0f;
#pragma unroll 8
        for (int i = 0; i < HD; i++) {
            float z = sH[local][i];
            a = fmaf(z, eW1n[i * HD + ch], a);
            b = fmaf(z, eW1n[(HD + i) * HD + ch], b);
        }
        Hrh[(size_t)n * HD + ch] = __float2half(a);
        Hch[(size_t)n * HD + ch] = __float2half(b);
    } else {
        sH[local][ch] = hn;
        __syncthreads();
        float o0 = bout[ch], o1 = bout[HD + ch];
#pragma unroll 8
        for (int i = 0; i < HD; i++) {
            float z = sH[local][i];
            o0 = fmaf(z, Wout[i * COUT + ch], o0);
            o1 = fmaf(z, Wout[i * COUT + HD + ch], o1);
        }
        out[(size_t)n * COUT + ch]      = o0;
        out[(size_t)n * COUT + HD + ch] = o1;
    }
}

extern "C" void kernel_launch(void* const* d_in, const int* in_sizes, int n_in,
                              void* d_out, int out_size, void* d_ws, size_t ws_size,
                              hipStream_t stream) {
    // setup_inputs() dict insertion order:
    //  0 data, 1 pos, 2 edge_attr, 3 t, 4 row, 5 col,
    //  6 emb_in_w, 7 emb_in_b, 8 emb_out_w, 9 emb_out_b,
    // 10 edge_w1, 11 edge_b1, 12 edge_w2, 13 edge_b2,
    // 14 node_w1, 15 node_b1, 16 node_w2, 17 node_b2,
    // 18 coord_w1, 19 coord_b1, 20 coord_w2
    const float* data      = (const float*)d_in[0];
    const float* pos       = (const float*)d_in[1];
    const float* edge_attr = (const float*)d_in[2];
    const float* tptr      = (const float*)d_in[3];
    const int*   row       = (const int*)d_in[4];
    const int*   col       = (const int*)d_in[5];
    const float* emb_in_w  = (const float*)d_in[6];
    const float* emb_in_b  = (const float*)d_in[7];
    const float* emb_out_w = (const float*)d_in[8];
    const float* emb_out_b = (const float*)d_in[9];
    const float* edge_w1   = (const float*)d_in[10];
    const float* edge_b1   = (const float*)d_in[11];
    const float* edge_w2   = (const float*)d_in[12];
    const float* edge_b2   = (const float*)d_in[13];
    const float* node_w1   = (const float*)d_in[14];
    const float* node_b1   = (const float*)d_in[15];
    const float* node_w2   = (const float*)d_in[16];
    const float* node_b2   = (const float*)d_in[17];
    const float* coord_w1  = (const float*)d_in[18];
    const float* coord_b1  = (const float*)d_in[19];
    const float* coord_w2  = (const float*)d_in[20];
    float* out = (float*)d_out;

    // workspace layout (float elements); ~11.9M floats = 47.6 MB
    float* ws = (float*)d_ws;
    float* h      = ws;                       // 1,600,000
    float* x4     = ws + 1600000;             //   200,000
    __half* Hrh   = (__half*)(ws + 1800000);  // 800,000 floats
    __half* Hch   = (__half*)(ws + 2600000);  // 800,000
    float* aggM   = ws + 3400000;             // 1,600,000
    float* aggX4  = ws + 5000000;             //   200,000
    int* rowstart = (int*)(ws + 5200000);     // NN+1
    int* bbase    = (int*)(ws + 5250204);     // NBUK+1
    int* resv     = (int*)(ws + 5250404);     // 256*NBUK
    int4* sedge   = (int4*)(ws + 5400000);    // NE int4
    int4* tmp     = (int4*)(ws + 8600000);    // NE int4
    __half* w2B   = (__half*)(ws + 11800000); // NL*2*64*8 halfs
    __half* cW1B  = w2B + (size_t)NL * 1024;

    prologue_kernel<<<EMB_BLKS + 256 + 1, 256, 0, stream>>>(
        data, pos, tptr, emb_in_w, emb_in_b, edge_w1 /*layer 0*/,
        row, edge_w2, coord_w1,
        h, x4, Hrh, Hch, aggM, aggX4, resv, w2B, cW1B);
    sortS3_kernel<<<256, 256, 0, stream>>>(row, col, edge_attr, resv, tmp, bbase);
    sortS4_kernel<<<NBUK, 256, 0, stream>>>(tmp, bbase, sedge, rowstart);

    for (int l = 0; l < NL; l++) {
        edge_fused_kernel<<<NE / 256, 128, 0, stream>>>(
            x4, sedge, Hrh, Hch,
            edge_w1 + l * (2*HD+2) * HD, edge_b1 + l * HD,
            edge_b2 + l * HD,
            w2B + (size_t)l * 1024, cW1B + (size_t)l * 1024,
            coord_b1 + l * HD, coord_w2 + l * HD,
            rowstart, aggM, aggX4);
        bool lastl = (l + 1 == NL);
        node_fused_kernel<<<NN / 8, 256, 0, stream>>>(
            h, x4, aggM, aggX4, rowstart,
            node_w1 + l * 2 * HD * HD, node_b1 + l * HD,
            node_w2 + l * HD * HD,     node_b2 + l * HD,
            lastl ? nullptr : (edge_w1 + (l + 1) * (2*HD+2) * HD), Hrh, Hch,
            emb_out_w, emb_out_b, lastl ? out : nullptr);
    }
}

// Round 13
// 410.119 us; speedup vs baseline: 1.0783x; 1.0783x over previous
//
#include <hip/hip_runtime.h>
#include <hip/hip_fp16.h>

#define NN 50000
#define NE 800000
#define CIN 64
#define COUT 64
#define HD 32
#define NL 4
#define NBUK 196      // ceil(NN/256)
#define BUKSH 8       // bucket(r) = r >> 8
#define EPB 3125      // NE / 256 (exact)
#define MAXB 4864     // bucket capacity (mean 4096, sigma 64 -> 12 sigma headroom)
#define BLKE 128      // edges per block in edge_fused
#define EMB_BLKS 196  // ceil(NN/256)

typedef float f32x4 __attribute__((ext_vector_type(4)));
typedef _Float16 half8 __attribute__((ext_vector_type(8)));

__device__ __forceinline__ float silu_f(float v) {
    return v * __builtin_amdgcn_rcpf(1.0f + __expf(-v));
}

// ========== K1: fused prologue — embed (blocks 0..195) | S1 hist (196..451) | prep (452)
__global__ __launch_bounds__(256) void prologue_kernel(
    const float* __restrict__ data, const float* __restrict__ pos,
    const float* __restrict__ tptr,
    const float* __restrict__ W, const float* __restrict__ b,
    const float* __restrict__ eW1_0,
    const int* __restrict__ row,
    const float* __restrict__ eW2, const float* __restrict__ cW1,
    float* __restrict__ h, float* __restrict__ x4,
    __half* __restrict__ Hrh, __half* __restrict__ Hch,
    float* __restrict__ aggM, float* __restrict__ aggX4,
    int* __restrict__ resv,
    __half* __restrict__ w2B, __half* __restrict__ cW1B)
{
    int blk = blockIdx.x;
    int tid = threadIdx.x;

    if (blk < EMB_BLKS) {
        // ---------------- embed role ----------------
        int n = blk * 256 + tid;
        if (n >= NN) return;
        float t = tptr[0];
        float d[CIN];
        const float4* dp = (const float4*)(data + (size_t)n * CIN);
#pragma unroll
        for (int i = 0; i < CIN / 4; i++) {
            float4 v = dp[i];
            d[4*i+0] = v.x; d[4*i+1] = v.y; d[4*i+2] = v.z; d[4*i+3] = v.w;
        }
        float acc[HD];
#pragma unroll
        for (int j = 0; j < HD; j++) acc[j] = fmaf(t, W[j], b[j]);   // row 0 = t channel
#pragma unroll
        for (int i = 0; i < CIN; i++) {
            float a = d[i];
#pragma unroll
            for (int j = 0; j < HD; j++) acc[j] = fmaf(a, W[(i + 1) * HD + j], acc[j]);
        }
        float4* hp = (float4*)(h + (size_t)n * HD);
#pragma unroll
        for (int j = 0; j < HD / 4; j++)
            hp[j] = make_float4(acc[4*j], acc[4*j+1], acc[4*j+2], acc[4*j+3]);
        ((float4*)x4)[n] = make_float4(pos[n*2+0], pos[n*2+1], 0.0f, 0.0f);

        float a1[HD], a2[HD];
#pragma unroll
        for (int j = 0; j < HD; j++) { a1[j] = 0.0f; a2[j] = 0.0f; }
#pragma unroll
        for (int i = 0; i < HD; i++) {
            float z = acc[i];
#pragma unroll
            for (int j = 0; j < HD; j++) {
                a1[j] = fmaf(z, eW1_0[i * HD + j], a1[j]);
                a2[j] = fmaf(z, eW1_0[(HD + i) * HD + j], a2[j]);
            }
        }
        int w1[16], w2[16];
#pragma unroll
        for (int q = 0; q < 16; q++) {
            __half2 p1 = __floats2half2_rn(a1[2*q], a1[2*q+1]);
            __half2 p2 = __floats2half2_rn(a2[2*q], a2[2*q+1]);
            w1[q] = *(int*)&p1;
            w2[q] = *(int*)&p2;
        }
        int4* rp = (int4*)(Hrh + (size_t)n * HD);
        int4* cp = (int4*)(Hch + (size_t)n * HD);
#pragma unroll
        for (int q = 0; q < 4; q++) {
            rp[q] = make_int4(w1[4*q], w1[4*q+1], w1[4*q+2], w1[4*q+3]);
            cp[q] = make_int4(w2[4*q], w2[4*q+1], w2[4*q+2], w2[4*q+3]);
        }
        float4 z4 = make_float4(0.f, 0.f, 0.f, 0.f);
        float4* za = (float4*)(aggM + (size_t)n * HD);
#pragma unroll
        for (int j = 0; j < HD/4; j++) za[j] = z4;
        ((float4*)aggX4)[n] = z4;
    } else if (blk < EMB_BLKS + 256) {
        // ---------------- S1 role: per-chunk bucket histogram -> resv
        __shared__ int lb[256];
        int sb = blk - EMB_BLKS;
        lb[tid] = 0;
        __syncthreads();
        int base = sb * EPB;
        for (int i = tid; i < EPB; i += 256)
            atomicAdd(&lb[row[base + i] >> BUKSH], 1);
        __syncthreads();
        if (tid < NBUK) resv[sb * NBUK + tid] = lb[tid];
    } else {
        // ---------------- prep role: pack W2 / cW1 into MFMA B-fragment order (f16)
        if (tid >= 128) return;
        int nt = tid >> 6;
        int wl = tid & 63;
        int rsel = wl & 15, ksel = wl >> 4;
        for (int l = 0; l < NL; l++) {
#pragma unroll
            for (int e = 0; e < 8; e++) {
                int k = 8 * ksel + e;
                int j = 16 * nt + rsel;
                size_t o = ((size_t)(l * 2 + nt) * 64 + wl) * 8 + e;
                w2B[o]  = __float2half(eW2[(size_t)l * HD * HD + k * HD + j]);
                cW1B[o] = __float2half(cW1[(size_t)l * HD * HD + k * HD + j]);
            }
        }
    }
}

// ========== K2: S3' — partition into buckets; inline bucket scan from resv ==========
__global__ __launch_bounds__(256) void sortS3_kernel(
    const int* __restrict__ row, const int* __restrict__ col,
    const float* __restrict__ eattr,
    const int* __restrict__ resv,
    int4* __restrict__ tmp, int* __restrict__ bbase_g)
{
    __shared__ int4 st[EPB];           // 50 KB
    __shared__ int sd[256];
    __shared__ int lcnt_s[NBUK];
    __shared__ int lbex_s[NBUK];
    __shared__ int g_s[NBUK];
    __shared__ int lcur[NBUK];
    int tid = threadIdx.x;
    int bb = blockIdx.x;
    int base = bb * EPB;

    int myCnt = (tid < NBUK) ? resv[bb * NBUK + tid] : 0;
    if (tid < NBUK) { lcnt_s[tid] = myCnt; lcur[tid] = 0; }
    sd[tid] = myCnt;
    __syncthreads();
    for (int off = 1; off < 256; off <<= 1) {
        int t = (tid >= off) ? sd[tid - off] : 0;
        __syncthreads();
        sd[tid] += t;
        __syncthreads();
    }
    if (tid < NBUK) lbex_s[tid] = sd[tid] - myCnt;
    __syncthreads();

    int tot = 0, pre = 0;
    if (tid < NBUK) {
        for (int b2 = 0; b2 < 256; b2++) {
            int cv = resv[b2 * NBUK + tid];
            tot += cv;
            if (b2 < bb) pre += cv;
        }
    }
    sd[tid] = (tid < NBUK) ? tot : 0;
    __syncthreads();
    for (int off = 1; off < 256; off <<= 1) {
        int t = (tid >= off) ? sd[tid - off] : 0;
        __syncthreads();
        sd[tid] += t;
        __syncthreads();
    }
    if (tid < NBUK) {
        int bbase_k = sd[tid] - tot;
        g_s[tid] = bbase_k + pre;
        if (bb == 0) bbase_g[tid] = bbase_k;
    }
    if (bb == 0 && tid == 255) bbase_g[NBUK] = sd[255];   // == NE
    __syncthreads();

    for (int i = tid; i < EPB; i += 256) {
        int e = base + i;
        int r = row[e];
        int bk = r >> BUKSH;
        int p = lbex_s[bk] + atomicAdd(&lcur[bk], 1);
        st[p] = make_int4(r, col[e], __float_as_int(eattr[e]), 0);
    }
    __syncthreads();
    int wid = tid >> 6, lane = tid & 63;
    for (int k = wid; k < NBUK; k += 4) {
        int L = lcnt_s[k];
        int g = g_s[k];
        int o = lbex_s[k];
        for (int i = lane; i < L; i += 64)
            tmp[g + i] = st[o + i];
    }
}

// ========== K3: S4 — within-bucket node sort; rowstart + sedge coalesced ==========
__global__ __launch_bounds__(256) void sortS4_kernel(
    const int4* __restrict__ tmp, const int* __restrict__ bbase,
    int4* __restrict__ sedge, int* __restrict__ rowstart)
{
    __shared__ int4 st[MAXB];          // 76 KB
    __shared__ int lcnt[256], lex[256], lcur[256], sd[256];
    int tid = threadIdx.x;
    int k = blockIdx.x;
    int lo = bbase[k], hi = bbase[k + 1];
    int nE = hi - lo;
    int nodeBase = k << BUKSH;
    lcnt[tid] = 0; lcur[tid] = 0;
    __syncthreads();
    for (int i = tid; i < nE; i += 256)
        atomicAdd(&lcnt[tmp[lo + i].x - nodeBase], 1);
    __syncthreads();
    int v = lcnt[tid];
    sd[tid] = v;
    __syncthreads();
    for (int off = 1; off < 256; off <<= 1) {
        int t = (tid >= off) ? sd[tid - off] : 0;
        __syncthreads();
        sd[tid] += t;
        __syncthreads();
    }
    lex[tid] = sd[tid] - v;
    int n = nodeBase + tid;
    if (n < NN) rowstart[n] = lo + lex[tid];
    if (k == NBUK - 1 && tid == 0) rowstart[NN] = NE;
    __syncthreads();
    for (int i = tid; i < nE; i += 256) {
        int4 e = tmp[lo + i];
        int ln = e.x - nodeBase;
        int p = lex[ln] + atomicAdd(&lcur[ln], 1);
        st[p] = e;
    }
    __syncthreads();
    for (int i = tid; i < nE; i += 256)
        sedge[lo + i] = st[i];
}

// ------- fused edge kernel (128 edges/block): VALU epilogue + MFMA + segmented agg ----
__global__ __launch_bounds__(128, 8) void edge_fused_kernel(
    const float* __restrict__ x4,
    const int4* __restrict__ sedge,
    const __half* __restrict__ Hrh, const __half* __restrict__ Hch,
    const float* __restrict__ eW1, const float* __restrict__ eb1,
    const float* __restrict__ eb2,
    const __half* __restrict__ w2Bl, const __half* __restrict__ cW1Bl,
    const float* __restrict__ cb1, const float* __restrict__ cW2,
    const int* __restrict__ rowstart,
    float* __restrict__ aggM, float* __restrict__ aggX4)
{
    __shared__ __align__(16) __half At[BLKE][40];  // t1 (f16), then reused for m (f16)
    __shared__ __half sx[BLKE][4];                 // d*phi
    __shared__ float  phib[BLKE];
    __shared__ int snf, snl;
    int tid = threadIdx.x;
    int s_base = blockIdx.x * BLKE;
    int s = s_base + tid;                          // NE % 128 == 0
    int4 ei = sedge[s];
    int r = ei.x, c = ei.y;
    float ea = __int_as_float(ei.z);
    if (tid == 0)        snf = r;
    if (tid == BLKE - 1) snl = r;

    float4 xr = ((const float4*)x4)[r];
    float4 xc = ((const float4*)x4)[c];
    float d0 = xr.x - xc.x, d1 = xr.y - xc.y, d2 = xr.z - xc.z;
    float radial = d0*d0 + d1*d1 + d2*d2;

    // ---- P1: t1 = silu(Hr[r] + Hc[c] + radial*W1[64,:] + ea*W1[65,:] + b1) -> LDS f16
    const half8* hr8 = (const half8*)(Hrh + (size_t)r * HD);
    const half8* hc8 = (const half8*)(Hch + (size_t)c * HD);
    int wbuf[16];
#pragma unroll
    for (int i = 0; i < 4; i++) {
        half8 s8 = hr8[i] + hc8[i];          // v_pk_add_f16
#pragma unroll
        for (int kk = 0; kk < 8; kk += 2) {
            int j = 8*i + kk;
            float v0 = (float)s8[kk]   + eb1[j]   + radial * eW1[64*HD+j]   + ea * eW1[65*HD+j];
            float v1 = (float)s8[kk+1] + eb1[j+1] + radial * eW1[64*HD+j+1] + ea * eW1[65*HD+j+1];
            __half2 p = __floats2half2_rn(silu_f(v0), silu_f(v1));
            wbuf[(j >> 1)] = *(int*)&p;
        }
    }
    int4* arow = (int4*)&At[tid][0];
#pragma unroll
    for (int q = 0; q < 4; q++)
        arow[q] = make_int4(wbuf[4*q], wbuf[4*q+1], wbuf[4*q+2], wbuf[4*q+3]);

    int wl = tid & 63;
    int wbase = tid & 64;            // wave's private 64-row LDS window
    int rsel = wl & 15, ksel = wl >> 4;

    // ---- P2: GEMM2 via MFMA: M[64,32] = At[64,32] @ W2 + b2, silu -> m (back to LDS)
    half8 bw0 = ((const half8*)w2Bl)[wl];
    half8 bw1 = ((const half8*)w2Bl)[64 + wl];
    float bc0 = eb2[rsel], bc1 = eb2[16 + rsel];
    f32x4 acc[4][2];
#pragma unroll
    for (int mt = 0; mt < 4; mt++) {
        acc[mt][0] = (f32x4){bc0, bc0, bc0, bc0};
        acc[mt][1] = (f32x4){bc1, bc1, bc1, bc1};
    }
    __builtin_amdgcn_s_setprio(1);
#pragma unroll
    for (int mt = 0; mt < 4; mt++) {
        half8 af = *(const half8*)&At[wbase + 16*mt + rsel][8*ksel];
        acc[mt][0] = __builtin_amdgcn_mfma_f32_16x16x32_f16(af, bw0, acc[mt][0], 0, 0, 0);
        acc[mt][1] = __builtin_amdgcn_mfma_f32_16x16x32_f16(af, bw1, acc[mt][1], 0, 0, 0);
    }
    __builtin_amdgcn_s_setprio(0);
#pragma unroll
    for (int mt = 0; mt < 4; mt++)
#pragma unroll
        for (int nt = 0; nt < 2; nt++)
#pragma unroll
            for (int q = 0; q < 4; q++) {
                float mv = silu_f(acc[mt][nt][q]);
                At[wbase + 16*mt + 4*ksel + q][16*nt + rsel] = __float2half(mv);
            }

    // ---- P3: coord MLP via MFMA: C1[64,32] = m @ cW1 + cb1
    half8 cw0 = ((const half8*)cW1Bl)[wl];
    half8 cw1 = ((const half8*)cW1Bl)[64 + wl];
    float cc0 = cb1[rsel], cc1 = cb1[16 + rsel];
    f32x4 cacc[4][2];
#pragma unroll
    for (int mt = 0; mt < 4; mt++) {
        cacc[mt][0] = (f32x4){cc0, cc0, cc0, cc0};
        cacc[mt][1] = (f32x4){cc1, cc1, cc1, cc1};
    }
    __builtin_amdgcn_s_setprio(1);
#pragma unroll
    for (int mt = 0; mt < 4; mt++) {
        half8 am = *(const half8*)&At[wbase + 16*mt + rsel][8*ksel];
        cacc[mt][0] = __builtin_amdgcn_mfma_f32_16x16x32_f16(am, cw0, cacc[mt][0], 0, 0, 0);
        cacc[mt][1] = __builtin_amdgcn_mfma_f32_16x16x32_f16(am, cw1, cacc[mt][1], 0, 0, 0);
    }
    __builtin_amdgcn_s_setprio(0);

    // ---- P4: phi[row] = sum_j silu(C1[row][j]) * cW2[j]; reduce across 16-lane cols
    float cw2a = cW2[rsel], cw2b = cW2[16 + rsel];
    float p[4][4];
#pragma unroll
    for (int mt = 0; mt < 4; mt++)
#pragma unroll
        for (int q = 0; q < 4; q++)
            p[mt][q] = silu_f(cacc[mt][0][q]) * cw2a + silu_f(cacc[mt][1][q]) * cw2b;
#pragma unroll
    for (int dd = 1; dd < 16; dd <<= 1)
#pragma unroll
        for (int mt = 0; mt < 4; mt++)
#pragma unroll
            for (int q = 0; q < 4; q++)
                p[mt][q] += __shfl_xor(p[mt][q], dd);
    if (rsel == 0) {
#pragma unroll
        for (int mt = 0; mt < 4; mt++)
#pragma unroll
            for (int q = 0; q < 4; q++)
                phib[wbase + 16*mt + 4*ksel + q] = p[mt][q];
    }
    float phi = phib[tid];

    *(__half2*)&sx[tid][0] = __floats2half2_rn(d0 * phi, d1 * phi);
    sx[tid][2] = __float2half(d2 * phi);
    __syncthreads();

    // ---- P5: block-segmented reduction (m read from At as f16); 4 lane-groups
    int g = tid >> 5, ch = tid & 31;
    int nf = snf, nl = snl;
    for (int node = nf + g; node <= nl; node += 4) {
        int lo = rowstart[node], hi = rowstart[node + 1];
        int clo = lo - s_base; if (clo < 0) clo = 0;
        int chi = hi - s_base; if (chi > BLKE) chi = BLKE;
        if (chi <= clo) continue;                       // zero-degree node in range
        float am = 0.0f;
        for (int j = clo; j < chi; j++) am += __half2float(At[j][ch]);
        bool interior = (lo >= s_base) && (hi <= s_base + BLKE);
        if (interior) aggM[(size_t)node * HD + ch] = am;
        else          atomicAdd(&aggM[(size_t)node * HD + ch], am);
        if (ch < 3) {
            float ax = 0.0f;
            for (int j = clo; j < chi; j++) ax += __half2float(sx[j][ch]);
            if (interior) aggX4[(size_t)node * 4 + ch] = ax;
            else          atomicAdd(&aggX4[(size_t)node * 4 + ch], ax);
        }
    }
}

// ------- node update (+ f16 Hr/Hc for next layer, or fused output projection) -------
__global__ __launch_bounds__(256) void node_fused_kernel(
    float* __restrict__ h, float* __restrict__ x4,
    float* __restrict__ aggM, float* __restrict__ aggX4,
    const int* __restrict__ rowstart,
    const float* __restrict__ nW1, const float* __restrict__ nb1,
    const float* __restrict__ nW2, const float* __restrict__ nb2,
    const float* __restrict__ eW1n,   // next layer edge_w1 (null on last layer)
    __half* __restrict__ Hrh, __half* __restrict__ Hch,
    const float* __restrict__ Wout, const float* __restrict__ bout,
    float* __restrict__ out)          // non-null on last layer
{
    __shared__ float sIn[8][2*HD];
    __shared__ float sU[8][HD];
    __shared__ float sH[8][HD];
    int local = threadIdx.x >> 5;
    int ch    = threadIdx.x & 31;
    int n = blockIdx.x * 8 + local;          // NN == 6250*8, exact
    float hv = h[(size_t)n * HD + ch];
    float am = aggM[(size_t)n * HD + ch];
    aggM[(size_t)n * HD + ch] = 0.0f;        // re-zero for next layer's boundary atomics
    sIn[local][ch]      = hv;
    sIn[local][HD + ch] = am;
    if (ch < 3) {
        int cnt = rowstart[n + 1] - rowstart[n];
        float cf = (cnt < 1) ? 1.0f : (float)cnt;
        x4[(size_t)n * 4 + ch] += aggX4[(size_t)n * 4 + ch] / cf;
        aggX4[(size_t)n * 4 + ch] = 0.0f;
    }
    __syncthreads();
    float u1 = nb1[ch];
#pragma unroll 8
    for (int i = 0; i < 2*HD; i++) u1 = fmaf(sIn[local][i], nW1[i * HD + ch], u1);
    u1 = silu_f(u1);
    sU[local][ch] = u1;
    __syncthreads();
    float u2 = nb2[ch];
#pragma unroll 8
    for (int i = 0; i < HD; i++) u2 = fmaf(sU[local][i], nW2[i * HD + ch], u2);
    float hn = hv + u2;

    if (eW1n != nullptr) {
        h[(size_t)n * HD + ch] = hn;
        sH[local][ch] = hn;
        __syncthreads();
        float a = 0.0f, b = 0.0f;
#pragma unroll 8
        for (int i = 0; i < HD; i++) {
            float z = sH[local][i];
            a = fmaf(z, eW1n[i * HD + ch], a);
            b = fmaf(z, eW1n[(HD + i) * HD + ch], b);
        }
        Hrh[(size_t)n * HD + ch] = __float2half(a);
        Hch[(size_t)n * HD + ch] = __float2half(b);
    } else {
        sH[local][ch] = hn;
        __syncthreads();
        float o0 = bout[ch], o1 = bout[HD + ch];
#pragma unroll 8
        for (int i = 0; i < HD; i++) {
            float z = sH[local][i];
            o0 = fmaf(z, Wout[i * COUT + ch], o0);
            o1 = fmaf(z, Wout[i * COUT + HD + ch], o1);
        }
        out[(size_t)n * COUT + ch]      = o0;
        out[(size_t)n * COUT + HD + ch] = o1;
    }
}

extern "C" void kernel_launch(void* const* d_in, const int* in_sizes, int n_in,
                              void* d_out, int out_size, void* d_ws, size_t ws_size,
                              hipStream_t stream) {
    // setup_inputs() dict insertion order:
    //  0 data, 1 pos, 2 edge_attr, 3 t, 4 row, 5 col,
    //  6 emb_in_w, 7 emb_in_b, 8 emb_out_w, 9 emb_out_b,
    // 10 edge_w1, 11 edge_b1, 12 edge_w2, 13 edge_b2,
    // 14 node_w1, 15 node_b1, 16 node_w2, 17 node_b2,
    // 18 coord_w1, 19 coord_b1, 20 coord_w2
    const float* data      = (const float*)d_in[0];
    const float* pos       = (const float*)d_in[1];
    const float* edge_attr = (const float*)d_in[2];
    const float* tptr      = (const float*)d_in[3];
    const int*   row       = (const int*)d_in[4];
    const int*   col       = (const int*)d_in[5];
    const float* emb_in_w  = (const float*)d_in[6];
    const float* emb_in_b  = (const float*)d_in[7];
    const float* emb_out_w = (const float*)d_in[8];
    const float* emb_out_b = (const float*)d_in[9];
    const float* edge_w1   = (const float*)d_in[10];
    const float* edge_b1   = (const float*)d_in[11];
    const float* edge_w2   = (const float*)d_in[12];
    const float* edge_b2   = (const float*)d_in[13];
    const float* node_w1   = (const float*)d_in[14];
    const float* node_b1   = (const float*)d_in[15];
    const float* node_w2   = (const float*)d_in[16];
    const float* node_b2   = (const float*)d_in[17];
    const float* coord_w1  = (const float*)d_in[18];
    const float* coord_b1  = (const float*)d_in[19];
    const float* coord_w2  = (const float*)d_in[20];
    float* out = (float*)d_out;

    // workspace layout (float elements); ~11.9M floats = 47.6 MB
    float* ws = (float*)d_ws;
    float* h      = ws;                       // 1,600,000
    float* x4     = ws + 1600000;             //   200,000
    __half* Hrh   = (__half*)(ws + 1800000);  // 800,000 floats
    __half* Hch   = (__half*)(ws + 2600000);  // 800,000
    float* aggM   = ws + 3400000;             // 1,600,000
    float* aggX4  = ws + 5000000;             //   200,000
    int* rowstart = (int*)(ws + 5200000);     // NN+1
    int* bbase    = (int*)(ws + 5250204);     // NBUK+1
    int* resv     = (int*)(ws + 5250404);     // 256*NBUK
    int4* sedge   = (int4*)(ws + 5400000);    // NE int4
    int4* tmp     = (int4*)(ws + 8600000);    // NE int4
    __half* w2B   = (__half*)(ws + 11800000); // NL*2*64*8 halfs
    __half* cW1B  = w2B + (size_t)NL * 1024;

    prologue_kernel<<<EMB_BLKS + 256 + 1, 256, 0, stream>>>(
        data, pos, tptr, emb_in_w, emb_in_b, edge_w1 /*layer 0*/,
        row, edge_w2, coord_w1,
        h, x4, Hrh, Hch, aggM, aggX4, resv, w2B, cW1B);
    sortS3_kernel<<<256, 256, 0, stream>>>(row, col, edge_attr, resv, tmp, bbase);
    sortS4_kernel<<<NBUK, 256, 0, stream>>>(tmp, bbase, sedge, rowstart);

    for (int l = 0; l < NL; l++) {
        edge_fused_kernel<<<NE / BLKE, BLKE, 0, stream>>>(
            x4, sedge, Hrh, Hch,
            edge_w1 + l * (2*HD+2) * HD, edge_b1 + l * HD,
            edge_b2 + l * HD,
            w2B + (size_t)l * 1024, cW1B + (size_t)l * 1024,
            coord_b1 + l * HD, coord_w2 + l * HD,
            rowstart, aggM, aggX4);
        bool lastl = (l + 1 == NL);
        node_fused_kernel<<<NN / 8, 256, 0, stream>>>(
            h, x4, aggM, aggX4, rowstart,
            node_w1 + l * 2 * HD * HD, node_b1 + l * HD,
            node_w2 + l * HD * HD,     node_b2 + l * HD,
            lastl ? nullptr : (edge_w1 + (l + 1) * (2*HD+2) * HD), Hrh, Hch,
            emb_out_w, emb_out_b, lastl ? out : nullptr);
    }
}